// Round 3
// baseline (429.266 us; speedup 1.0000x reference)
//
#include <hip/hip_runtime.h>
#include <hip/hip_bf16.h>
#include <hip/hip_fp16.h>

#define N_NODES 200000
#define N_EDGES 500000
#define F_IN    165
#define HID     256
#define SX      192   // padded f16 row stride (24 half8 segs, 16B-aligned rows)
#define NB      782   // ceil(N_NODES/256) scan blocks

typedef float    floatx4 __attribute__((ext_vector_type(4)));
typedef float    floatx4a __attribute__((ext_vector_type(4), aligned(16)));
typedef float    float4u __attribute__((ext_vector_type(4), aligned(4)));
typedef _Float16 half8   __attribute__((ext_vector_type(8)));

// ---------- K0: x (f32, stride 165) -> xh (f16 half8 segs, stride 24) ----------
__global__ void cast_x_kernel(const float* __restrict__ x, half8* __restrict__ xh8) {
    int idx = blockIdx.x * blockDim.x + threadIdx.x;   // < N*24
    int row = idx / 24;
    int p = idx - row * 24;
    int f0 = p * 8;
    const float* px = x + (long)row * F_IN + f0;
    half8 r;
    if (f0 + 8 <= F_IN) {
        float4u lo = *(const float4u*)px;
        float4u hi = *(const float4u*)(px + 4);
#pragma unroll
        for (int q = 0; q < 4; ++q) r[q] = (_Float16)lo[q];
#pragma unroll
        for (int q = 0; q < 4; ++q) r[4 + q] = (_Float16)hi[q];
    } else {
#pragma unroll
        for (int q = 0; q < 8; ++q)
            r[q] = (f0 + q < F_IN) ? (_Float16)px[q] : (_Float16)0.0f;
    }
    xh8[idx] = r;
}

// ---------- K1: dst-degree histogram ----------
__global__ void hist_kernel(const int* __restrict__ ei, int* __restrict__ degi) {
    int e = blockIdx.x * blockDim.x + threadIdx.x;
    if (e < N_EDGES) atomicAdd(&degi[ei[N_EDGES + e]], 1);
}

// ---------- K2a: per-block degree sums ----------
__global__ __launch_bounds__(256) void block_sum_kernel(const int* __restrict__ degi,
                                                        int* __restrict__ bsum) {
    __shared__ int sh[256];
    int t = threadIdx.x, i = blockIdx.x * 256 + t;
    sh[t] = (i < N_NODES) ? degi[i] : 0;
    __syncthreads();
#pragma unroll
    for (int off = 128; off > 0; off >>= 1) {
        if (t < off) sh[t] += sh[t + off];
        __syncthreads();
    }
    if (t == 0) bsum[blockIdx.x] = sh[0];
}

// ---------- K2b: scan the 782 block sums (1 block) ----------
__global__ __launch_bounds__(1024) void scan_bsum_kernel(const int* __restrict__ bsum,
                                                         int* __restrict__ boff,
                                                         int* __restrict__ row_start) {
    __shared__ int sh[1024];
    int t = threadIdx.x;
    int v = (t < NB) ? bsum[t] : 0;
    sh[t] = v;
    __syncthreads();
    for (int off = 1; off < 1024; off <<= 1) {
        int u = (t >= off) ? sh[t - off] : 0;
        __syncthreads();
        sh[t] += u;
        __syncthreads();
    }
    if (t < NB) boff[t] = sh[t] - v;               // exclusive
    if (t == 1023) row_start[N_NODES] = sh[1023];  // total = E
}

// ---------- K2c: emit row_start / cursor / invdeg ----------
__global__ __launch_bounds__(256) void scan_emit_kernel(const int* __restrict__ degi,
                                                        const int* __restrict__ boff,
                                                        int* __restrict__ row_start,
                                                        int* __restrict__ cursor,
                                                        float* __restrict__ invdeg) {
    __shared__ int sh[256];
    int t = threadIdx.x, i = blockIdx.x * 256 + t;
    int d = (i < N_NODES) ? degi[i] : 0;
    sh[t] = d;
    __syncthreads();
#pragma unroll
    for (int off = 1; off < 256; off <<= 1) {
        int u = (t >= off) ? sh[t - off] : 0;
        __syncthreads();
        sh[t] += u;
        __syncthreads();
    }
    if (i < N_NODES) {
        int row = boff[blockIdx.x] + sh[t] - d;    // exclusive scan value
        row_start[i] = row;
        cursor[i] = row;
        invdeg[i] = 1.0f / fmaxf((float)d, 1.0f);
    }
}

// ---------- K3: bucket edges into CSR ----------
__global__ void scatter_edges_kernel(const int* __restrict__ ei,
                                     int* __restrict__ cursor,
                                     int* __restrict__ csr) {
    int e = blockIdx.x * blockDim.x + threadIdx.x;
    if (e >= N_EDGES) return;
    int s = ei[e];
    int d = ei[N_EDGES + e];
    int pos = atomicAdd(&cursor[d], 1);
    csr[pos] = s;
}

// ---------- K4: gather-aggregate (NO atomics): aggh[n] = sum xh[src] ----------
__global__ void gather_agg_kernel(const half8* __restrict__ xh8,
                                  const int* __restrict__ row_start,
                                  const int* __restrict__ csr,
                                  half8* __restrict__ aggh8) {
    int idx = blockIdx.x * blockDim.x + threadIdx.x;   // < N*24
    int n = idx / 24;
    int p = idx - n * 24;
    int e0 = row_start[n], e1 = row_start[n + 1];
    half8 acc = {0, 0, 0, 0, 0, 0, 0, 0};
    half8 acc2 = {0, 0, 0, 0, 0, 0, 0, 0};
    int e = e0;
    for (; e + 2 <= e1; e += 2) {
        int s0 = csr[e], s1 = csr[e + 1];
        half8 v0 = xh8[(long)s0 * 24 + p];
        half8 v1 = xh8[(long)s1 * 24 + p];
        acc += v0;
        acc2 += v1;
    }
    if (e < e1) acc += xh8[(long)csr[e] * 24 + p];
    aggh8[idx] = acc + acc2;
}

// ---------- K5: pack [w1_l | w1_r] (f16) into MFMA fragment order ----------
// Layout is the (row<->col mirrored) same for A- and B-operand use: lane ->
// (n = lane&15, k = (lane>>4)*8 + q). Used as A-operand in the swapped GEMM.
__global__ void prep_bfrag_kernel(const float* __restrict__ w1l,
                                  const float* __restrict__ w1r,
                                  _Float16* __restrict__ bfrag) {
    int gid = blockIdx.x * blockDim.x + threadIdx.x;
    if (gid >= 12 * 16 * 64) return;
    int lane = gid & 63;
    int j = (gid >> 6) & 15;
    int c = gid >> 10;
    int quad = lane >> 4, n = lane & 15;
    const float* w = (c < 6) ? w1l : w1r;
    int kb = (c < 6 ? c : c - 6) * 32;
    int col = j * 16 + n;
    half8 r;
#pragma unroll
    for (int q = 0; q < 8; ++q) {
        int k = kb + quad * 8 + q;
        r[q] = (_Float16)((k < F_IN) ? w[k * HID + col] : 0.0f);
    }
    *(half8*)(bfrag + gid * 8) = r;
}

// ---------- K6: fused MFMA GEMM + invdeg + bias + relu + layer-2 projection ----------
// SWAPPED-OPERAND form (T12 mechanism): acc[i][nt] = mfma(bfrag_i, xfrag_nt, acc)
// computes h^T, so C-layout is col=lane&15 -> NODE row, row=(lane>>4)*4+reg -> HID col.
// The layer-2 hid-reduction becomes per-lane FMAs + 2 shfl steps (32 shuffles/thread
// vs 256 ds_bpermute before) -- removes ~26us of DS-pipe occupancy (the hidden pipe:
// not visible in VALUBusy/MfmaUtil). a/b read patterns are identical to the unswapped
// version; invdeg becomes one scalar per lane per node-tile.
__global__ __launch_bounds__(512, 4) void gemm_fused_kernel(
        const _Float16* __restrict__ xh, const _Float16* __restrict__ aggh,
        const float* __restrict__ invdeg, const _Float16* __restrict__ bfrag,
        const float* __restrict__ b1,
        const float* __restrict__ w2l, const float* __restrict__ w2r,
        float* __restrict__ tl, float* __restrict__ tr) {
    __shared__ __attribute__((aligned(16))) _Float16 As[2][128 * 64];  // 2 x 16KB (pair buffers)
    __shared__ float tlr[128][4];
    const int tid = threadIdx.x;
    const int w = tid >> 6, lane = tid & 63;
    const int quad = lane >> 4, l15 = lane & 15;
    const int rowbase = blockIdx.x * 128;
    const int rhalf = (w & 1) * 64;        // node-half of this wave
    const int hidg = (w >> 1);             // hid-group (64 cols each)

    ((float*)tlr)[tid] = 0.0f;   // 512 floats, one per thread

    // staging: thread -> (row = tid>>2, seg = (tid&3)^swz), LDS slot = tid*16B (lane-linear DMA)
    const int srow_l = tid >> 2;
    const int sseg = (tid & 3) ^ ((srow_l >> 1) & 3);
    int srow = rowbase + srow_l;
    if (srow >= N_NODES) srow = N_NODES - 1;
    const int sgoff = srow * SX + sseg * 8;        // in halfs
    const int ldst = (tid & ~63) * 16;             // byte offset of this wave's 1KB stripe

    // node-fragment LDS byte offsets (B-operand): row = rhalf + nt*16 + l15, k-seg = quad
    int aoff[4];
#pragma unroll
    for (int nt = 0; nt < 4; ++nt) {
        int r = rhalf + nt * 16 + l15;
        int slot = r * 4 + (quad ^ ((r >> 1) & 3));
        aoff[nt] = slot * 16;
    }
    // bfrag per-thread byte offset (A-operand): tile index cc*16 + hidg*4 + i
    const int boff = (hidg * 4 * 64 + lane) * 16;

    floatx4 acc[4][4];   // [i = hid tile][nt = node tile]
#pragma unroll
    for (int i = 0; i < 4; ++i)
#pragma unroll
        for (int nt = 0; nt < 4; ++nt)
            acc[i][nt] = (floatx4){0.f, 0.f, 0.f, 0.f};

    auto STAGE = [&](int p) {
#pragma unroll
        for (int u = 0; u < 2; ++u) {
            const int cc = 2 * p + u;
            const _Float16* src = (cc < 6) ? aggh : xh;          // wave-uniform select
            const int kb = (cc < 6 ? cc : cc - 6) * 32;
            const _Float16* gp = src + sgoff + kb;
            char* dst = (char*)(&As[p & 1][u * 128 * 32]) + ldst;
            __builtin_amdgcn_global_load_lds(
                (const __attribute__((address_space(1))) void*)gp,
                (__attribute__((address_space(3))) void*)dst, 16, 0, 0);
        }
    };

    // ---- prologue: stage pair 0, wait, barrier ----
    STAGE(0);
    asm volatile("s_waitcnt vmcnt(0)" ::: "memory");
    __builtin_amdgcn_s_barrier();
    __builtin_amdgcn_sched_barrier(0);

#pragma unroll 1
    for (int t = 0; t < 6; ++t) {
        if (t < 5) STAGE(t + 1);                   // DMA flies under the MFMAs below
        const char* abase = (const char*)(&As[t & 1][0]);
#pragma unroll
        for (int u = 0; u < 2; ++u) {
            const int cc = 2 * t + u;
            half8 a[4], b[4];
#pragma unroll
            for (int nt = 0; nt < 4; ++nt)
                a[nt] = *(const half8*)(abase + u * 8192 + aoff[nt]);
#pragma unroll
            for (int i = 0; i < 4; ++i)
                b[i] = *(const half8*)((const char*)bfrag + boff + (cc * 16 + i) * 1024);
#pragma unroll
            for (int i = 0; i < 4; ++i)
#pragma unroll
                for (int nt = 0; nt < 4; ++nt)
                    acc[i][nt] = __builtin_amdgcn_mfma_f32_16x16x32_f16(b[i], a[nt], acc[i][nt], 0, 0, 0);
        }
        if (t == 2) {   // agg phase (cc 0..5) done: scale by invdeg (per-lane scalar now)
#pragma unroll
            for (int nt = 0; nt < 4; ++nt) {
                int r = rowbase + rhalf + nt * 16 + l15;
                float iv = (r < N_NODES) ? invdeg[r] : 0.0f;
#pragma unroll
                for (int i = 0; i < 4; ++i)
                    acc[i][nt] *= iv;
            }
        }
        // next pair's DMA landed + all waves done reading current pair
        asm volatile("s_waitcnt vmcnt(0)" ::: "memory");
        __builtin_amdgcn_s_barrier();
        __builtin_amdgcn_sched_barrier(0);
    }

    // ---- epilogue: hid-reduction is per-lane; only 2 shfl steps across quads ----
    float s[4][4];   // [nt][c] : c = {tl0, tl1, tr0, tr1}
#pragma unroll
    for (int nt = 0; nt < 4; ++nt)
#pragma unroll
        for (int c = 0; c < 4; ++c) s[nt][c] = 0.0f;

#pragma unroll
    for (int i = 0; i < 4; ++i) {
        const int j0 = hidg * 64 + i * 16 + quad * 4;   // this lane's 4 hid cols (reg 0..3)
        floatx4a bbv = *(const floatx4a*)(b1 + j0);
        floatx4a wlA = *(const floatx4a*)(w2l + j0 * 2);      // [j0][0],[j0][1],[j0+1][0],[j0+1][1]
        floatx4a wlB = *(const floatx4a*)(w2l + j0 * 2 + 4);  // [j0+2..j0+3]
        floatx4a wrA = *(const floatx4a*)(w2r + j0 * 2);
        floatx4a wrB = *(const floatx4a*)(w2r + j0 * 2 + 4);
#pragma unroll
        for (int nt = 0; nt < 4; ++nt) {
#pragma unroll
            for (int reg = 0; reg < 4; ++reg) {
                float v = fmaxf(acc[i][nt][reg] + bbv[reg], 0.0f);
                float wl0 = (reg < 2) ? wlA[(reg & 1) * 2]     : wlB[(reg & 1) * 2];
                float wl1 = (reg < 2) ? wlA[(reg & 1) * 2 + 1] : wlB[(reg & 1) * 2 + 1];
                float wr0 = (reg < 2) ? wrA[(reg & 1) * 2]     : wrB[(reg & 1) * 2];
                float wr1 = (reg < 2) ? wrA[(reg & 1) * 2 + 1] : wrB[(reg & 1) * 2 + 1];
                s[nt][0] += v * wl0;
                s[nt][1] += v * wl1;
                s[nt][2] += v * wr0;
                s[nt][3] += v * wr1;
            }
        }
    }
#pragma unroll
    for (int nt = 0; nt < 4; ++nt) {
#pragma unroll
        for (int c = 0; c < 4; ++c) {
            s[nt][c] += __shfl_xor(s[nt][c], 16, 64);
            s[nt][c] += __shfl_xor(s[nt][c], 32, 64);
        }
        if (quad == 0) {   // lanes 0..15 hold the full 64-hid partial for node row
            int rl = rhalf + nt * 16 + l15;
            atomicAdd(&tlr[rl][0], s[nt][0]);
            atomicAdd(&tlr[rl][1], s[nt][1]);
            atomicAdd(&tlr[rl][2], s[nt][2]);
            atomicAdd(&tlr[rl][3], s[nt][3]);
        }
    }
    __syncthreads();
    if (tid < 128) {
        int row = rowbase + tid;
        if (row < N_NODES) {
            tl[row * 2 + 0] = tlr[tid][0];
            tl[row * 2 + 1] = tlr[tid][1];
            tr[row * 2 + 0] = tlr[tid][2];
            tr[row * 2 + 1] = tlr[tid][3];
        }
    }
}

// ---------- K7: fused layer-2 gather + finalize (NO atomics) ----------
__global__ void gather_out_kernel(const int* __restrict__ row_start,
                                  const int* __restrict__ csr,
                                  const float* __restrict__ tl,
                                  const float* __restrict__ tr,
                                  const float* __restrict__ invdeg,
                                  const float* __restrict__ b2,
                                  float* __restrict__ out) {
    int i = blockIdx.x * blockDim.x + threadIdx.x;
    if (i >= N_NODES) return;
    int e0 = row_start[i], e1 = row_start[i + 1];
    float a0 = 0.f, a1 = 0.f;
    for (int e = e0; e < e1; ++e) {
        int s = csr[e];
        a0 += tl[s * 2 + 0];
        a1 += tl[s * 2 + 1];
    }
    float inv = invdeg[i];
    out[i * 2 + 0] = a0 * inv + tr[i * 2 + 0] + b2[0];
    out[i * 2 + 1] = a1 * inv + tr[i * 2 + 1] + b2[1];
}

// ---------- K8: edge_index -> f32 passthrough ----------
__global__ void cast_edges_kernel(const int* __restrict__ ei,
                                  float* __restrict__ out) {
    int i = blockIdx.x * blockDim.x + threadIdx.x;
    if (i < 2 * N_EDGES) out[i] = (float)ei[i];
}

// ---------- workspace layout (bytes) ----------
//   0          degi      800000   (memset 0)
//   800000     row_start 800016   (N+1 ints)
//   1600032    cursor    800000
//   2400032    invdeg    800000
//   3200032    csr       2000000
//   5200032    tl        1600000
//   6800032    tr        1600000
//   8400032    bsum      3200
//   8403232    boff      3200
//   8406432    bfrag     196608
//   8610000    aggh      76800000  (f16, stride SX)
//   85410000   xh        76800000  (f16, stride SX)
extern "C" void kernel_launch(void* const* d_in, const int* in_sizes, int n_in,
                              void* d_out, int out_size, void* d_ws, size_t ws_size,
                              hipStream_t stream) {
    const float* x    = (const float*)d_in[0];
    const int*   ei   = (const int*)d_in[1];
    const float* w1_l = (const float*)d_in[2];
    const float* w1_r = (const float*)d_in[3];
    const float* b1   = (const float*)d_in[4];
    const float* w2_l = (const float*)d_in[5];
    const float* w2_r = (const float*)d_in[6];
    const float* b2   = (const float*)d_in[7];

    char* ws = (char*)d_ws;
    int*   degi      = (int*)(ws);
    int*   row_start = (int*)(ws + 800000);
    int*   cursor    = (int*)(ws + 1600032);
    float* invdeg    = (float*)(ws + 2400032);
    int*   csr       = (int*)(ws + 3200032);
    float* tl        = (float*)(ws + 5200032);
    float* tr        = (float*)(ws + 6800032);
    int*   bsum      = (int*)(ws + 8400032);
    int*   boff      = (int*)(ws + 8403232);
    _Float16* bfrag  = (_Float16*)(ws + 8406432);
    _Float16* aggh   = (_Float16*)(ws + 8610000);
    _Float16* xh     = (_Float16*)(ws + 85410000);

    float* out = (float*)d_out;   // f32: logits [0,400000), edges [400000,1400000)

    (void)hipMemsetAsync(degi, 0, 800000, stream);

    cast_x_kernel<<<(N_NODES * 24) / 256, 256, 0, stream>>>(x, (half8*)xh);
    prep_bfrag_kernel<<<48, 256, 0, stream>>>(w1_l, w1_r, bfrag);

    hist_kernel<<<(N_EDGES + 255) / 256, 256, 0, stream>>>(ei, degi);
    block_sum_kernel<<<NB, 256, 0, stream>>>(degi, bsum);
    scan_bsum_kernel<<<1, 1024, 0, stream>>>(bsum, boff, row_start);
    scan_emit_kernel<<<NB, 256, 0, stream>>>(degi, boff, row_start, cursor, invdeg);
    scatter_edges_kernel<<<(N_EDGES + 255) / 256, 256, 0, stream>>>(ei, cursor, csr);

    gather_agg_kernel<<<(N_NODES * 24) / 256, 256, 0, stream>>>(
        (const half8*)xh, row_start, csr, (half8*)aggh);

    gemm_fused_kernel<<<(N_NODES + 127) / 128, 512, 0, stream>>>(
        xh, aggh, invdeg, bfrag, b1, w2_l, w2_r, tl, tr);

    gather_out_kernel<<<NB, 256, 0, stream>>>(row_start, csr, tl, tr, invdeg, b2, out);
    cast_edges_kernel<<<(2 * N_EDGES + 255) / 256, 256, 0, stream>>>(ei, out + 2 * N_NODES);
}